// Round 8
// baseline (631.865 us; speedup 1.0000x reference)
//
#include <hip/hip_runtime.h>
#include <hip/hip_bf16.h>
#include <hip/hip_cooperative_groups.h>

namespace cg = cooperative_groups;

#define N   20000
#define E   320000
#define H   64
#define EA  9
#define EPS 1e-5f
#define GRID 256
#define SXS 136   // LDS row stride (ushort)

typedef short s16x8 __attribute__((ext_vector_type(8)));
typedef float f32x4 __attribute__((ext_vector_type(4)));

// ws offsets (u32 units)
#define OFF_DEG    0
#define OFF_CNT1   20000
#define OFF_ATTR   40000
#define OFF_ROWPTR 220000
#define OFF_EPOS   240016
#define OFF_PK2    560016
#define OFF_HB     1200016
#define OFF_AGG    1840016
#define OFF_W0HI   3120016
#define OFF_W0LO   3122064
#define OFF_WBHI   3124112
#define OFF_WBLO   3136400
#define OFF_W2HI   3148688
#define OFF_W2LO   3160976
#define OFF_BSUM   3173264
#define OFF_BOFF   3173392
// end 3173520 u32 = 12.69 MB

static __device__ __forceinline__ ushort f2bf(float f) {
    union { float f; unsigned u; } v; v.f = f;
    unsigned r = (v.u + 0x7fffu + ((v.u >> 16) & 1u)) >> 16;
    return (ushort)r;
}
static __device__ __forceinline__ float bf2f(ushort h) {
    union { unsigned u; float f; } v; v.u = ((unsigned)h) << 16;
    return v.f;
}

#define STORE_HL(dh, dl, off, v) {                                              \
    ushort h0=f2bf((v).x),h1=f2bf((v).y),h2=f2bf((v).z),h3=f2bf((v).w);         \
    ushort l0=f2bf((v).x-bf2f(h0)),l1=f2bf((v).y-bf2f(h1)),                     \
           l2=f2bf((v).z-bf2f(h2)),l3=f2bf((v).w-bf2f(h3));                     \
    ushort4 hv; hv.x=h0;hv.y=h1;hv.z=h2;hv.w=h3;                                \
    ushort4 lv; lv.x=l0;lv.y=l1;lv.z=l2;lv.w=l3;                                \
    *(ushort4*)((dh)+(off))=hv; *(ushort4*)((dl)+(off))=lv; }

struct GP {
    const int* ei; const int* x; const float* eattr;
    const float* emb0; const float* We; const float* be;
    const float* W1; const float* b1; const float* gamma; const float* beta;
    const float* bnm; const float* bnv; const float* W2; const float* b2;
    const int* slip; const int* sltp;
    float* out;
    int* deg; int* cnt1; float* attr; int* rowptr; int* epos; int2* pk2;
    ushort* hb; float* aggF;
    ushort* w0hi; ushort* w0lo; ushort* wbhi; ushort* wblo;
    ushort* w2hi; ushort* w2lo;
    int* bsum; int* boff;
};

static __device__ __forceinline__ int blk_scan(int v, int tid, int* lds) {
    int lane = tid & 63, w = tid >> 6;
    int s = v;
    #pragma unroll
    for (int off = 1; off < 64; off <<= 1) {
        int t = __shfl_up(s, off);
        if (lane >= off) s += t;
    }
    if (lane == 63) lds[w] = s;
    __syncthreads();
    int woff = 0;
    #pragma unroll
    for (int i = 0; i < 3; ++i) if (i < w) woff += lds[i];
    int incl = woff + s;
    __syncthreads();
    return incl;
}

static __device__ __forceinline__ void count_work(const GP& p, int e) {
    int s = p.ei[e];
    p.epos[e] = atomicAdd(&p.deg[s], 1);
    int d = p.ei[E + e];
    int xv = p.x[d];
    if (xv) atomicAdd(&p.cnt1[s], xv);
}

static __device__ void wprep_work(const GP& p, int t) {
    if (t < 4096) {
        int n = t >> 5, k = t & 31;
        float v = 0.f;
        if (k < 2) {
            for (int m = 0; m < 64; ++m) v += p.emb0[k * 64 + m] * p.W1[m * 128 + n];
        } else if (k < 11) {
            int j = k - 2;
            for (int m = 0; m < 64; ++m) v += p.We[j * 64 + m] * p.W1[(64 + m) * 128 + n];
        } else if (k == 11) {
            for (int m = 0; m < 64; ++m) v += p.be[m] * p.W1[(64 + m) * 128 + n];
        } else if (k == 12) {
            float slt = (float)p.sltp[0]; int sli = p.slip[0];
            for (int m = 0; m < 64; ++m) v += p.We[sli * 64 + m] * p.W1[(64 + m) * 128 + n];
            v *= slt;
        }
        ushort h = f2bf(v);
        p.w0hi[t] = h; p.w0lo[t] = f2bf(v - bf2f(h));
    } else if (t < 4096 + 24576) {
        int t2 = t - 4096;
        int l = 1 + t2 / 12288, r = t2 % 12288;
        int n = r / 96, k = r % 96;
        const float* W1L = p.W1 + l * 16384;
        const float* WeL = p.We + l * EA * H;
        const float* beL = p.be + l * H;
        float v = 0.f;
        if (k < 64) {
            v = W1L[k * 128 + n];
        } else if (k < 73) {
            int j = k - 64;
            for (int m = 0; m < 64; ++m) v += WeL[j * 64 + m] * W1L[(64 + m) * 128 + n];
        } else if (k == 73) {
            for (int m = 0; m < 64; ++m) v += beL[m] * W1L[(64 + m) * 128 + n];
        } else if (k == 74) {
            float slt = (float)p.sltp[0]; int sli = p.slip[0];
            for (int m = 0; m < 64; ++m) v += WeL[sli * 64 + m] * W1L[(64 + m) * 128 + n];
            v *= slt;
        }
        ushort h = f2bf(v);
        p.wbhi[t2] = h; p.wblo[t2] = f2bf(v - bf2f(h));
    } else if (t < 4096 + 24576 + 24576) {
        int t2 = t - 4096 - 24576;
        int l = t2 / 8192, r = t2 % 8192;
        int n = r >> 7, k = r & 127;
        float v = p.W2[l * 8192 + k * 64 + n];
        ushort h = f2bf(v);
        p.w2hi[t2] = h; p.w2lo[t2] = f2bf(v - bf2f(h));
    }
}

static __device__ __forceinline__ void attr_work(const GP& p, int t) {
    int n = t >> 4, q = t & 15;
    if (q >= EA) return;
    int pp = p.rowptr[n], p1 = p.rowptr[n + 1];
    float s = 0.f;
    for (; pp + 4 <= p1; pp += 4) {
        int e0 = p.pk2[pp].y, e1 = p.pk2[pp + 1].y,
            e2 = p.pk2[pp + 2].y, e3 = p.pk2[pp + 3].y;
        float v0 = p.eattr[e0 * EA + q];
        float v1 = p.eattr[e1 * EA + q];
        float v2 = p.eattr[e2 * EA + q];
        float v3 = p.eattr[e3 * EA + q];
        s += v0; s += v1; s += v2; s += v3;
    }
    for (; pp < p1; ++pp) s += p.eattr[p.pk2[pp].y * EA + q];
    p.attr[n * EA + q] = s;
}

static __device__ void gather_phase(const GP& p, int tid, int bid, int nblk) {
    const int lane = tid & 63, w = tid >> 6;
    for (int g0 = bid; g0 < N / 4; g0 += nblk) {
        const int n = g0 * 4 + w;
        const int p0 = p.rowptr[n], p1 = p.rowptr[n + 1];
        float acc = bf2f(p.hb[n * H + lane]);
        int q = p0;
        for (; q + 8 <= p1; q += 8) {
            const int4* pv = (const int4*)(p.pk2 + q);
            int4 a = pv[0], b = pv[1], c = pv[2], d = pv[3];
            float v0 = bf2f(p.hb[a.x * H + lane]);
            float v1 = bf2f(p.hb[a.z * H + lane]);
            float v2 = bf2f(p.hb[b.x * H + lane]);
            float v3 = bf2f(p.hb[b.z * H + lane]);
            float v4 = bf2f(p.hb[c.x * H + lane]);
            float v5 = bf2f(p.hb[c.z * H + lane]);
            float v6 = bf2f(p.hb[d.x * H + lane]);
            float v7 = bf2f(p.hb[d.z * H + lane]);
            acc += v0; acc += v1; acc += v2; acc += v3;
            acc += v4; acc += v5; acc += v6; acc += v7;
        }
        for (; q < p1; ++q) acc += bf2f(p.hb[p.pk2[q].x * H + lane]);
        p.aggF[n * H + lane] = acc;
    }
}

// 32-row MFMA MLP tile (hi/lo bf16, 3-term). LDS: X then Z (barrier-separated).
static __device__ void mlp_tile(const GP& p, int tb, int tid, ushort* sm,
        const ushort* wBhi, const ushort* wBlo, int wk, int nK,
        const ushort* w2hiL, const ushort* w2loL,
        const float* b1L, const float* gL, const float* btL,
        const float* mnL, const float* vrL, const float* b2L,
        int mode, int relu_out, void* h_out, int store_bf16) {
    ushort* sHi = sm;
    ushort* sLo = sm + 32 * SXS;
    const int n0 = tb * 32;

    {   // ---- Phase A: build X hi/lo (8 threads/row) ----
        const int r = tid >> 3, u = tid & 7;
        const int n = n0 + r;
        ushort* dh = sHi + r * SXS;
        ushort* dl = sLo + r * SXS;
        if (mode == 1) {
            float4 a0 = *(const float4*)(p.aggF + n * H + u * 8);
            float4 a1 = *(const float4*)(p.aggF + n * H + u * 8 + 4);
            STORE_HL(dh, dl, u * 8, a0);
            STORE_HL(dh, dl, u * 8 + 4, a1);
            if (u == 0) {
                float c[16];
                #pragma unroll
                for (int j = 0; j < 16; ++j) c[j] = 0.f;
                #pragma unroll
                for (int j = 0; j < EA; ++j) c[j] = p.attr[n * EA + j];
                c[9]  = (float)(p.rowptr[n + 1] - p.rowptr[n] + 1);
                c[10] = 1.f;
                #pragma unroll
                for (int i = 0; i < 4; ++i) {
                    float4 v = make_float4(c[i*4], c[i*4+1], c[i*4+2], c[i*4+3]);
                    STORE_HL(dh, dl, 64 + i * 4, v);
                }
            } else if (u == 1) {
                float4 z = make_float4(0.f, 0.f, 0.f, 0.f);
                #pragma unroll
                for (int i = 0; i < 4; ++i) STORE_HL(dh, dl, 80 + i * 4, z);
            }
        } else {
            if (u == 0) {
                float c[16];
                #pragma unroll
                for (int j = 0; j < 16; ++j) c[j] = 0.f;
                int xv = p.x[n];
                int degv = p.rowptr[n + 1] - p.rowptr[n];
                int c1 = p.cnt1[n] + xv;
                c[0] = (float)(degv + 1 - c1);
                c[1] = (float)c1;
                #pragma unroll
                for (int j = 0; j < EA; ++j) c[2 + j] = p.attr[n * EA + j];
                c[11] = (float)(degv + 1);
                c[12] = 1.f;
                #pragma unroll
                for (int i = 0; i < 4; ++i) {
                    float4 v = make_float4(c[i*4], c[i*4+1], c[i*4+2], c[i*4+3]);
                    STORE_HL(dh, dl, i * 4, v);
                }
            } else if (u == 1) {
                float4 z = make_float4(0.f, 0.f, 0.f, 0.f);
                #pragma unroll
                for (int i = 0; i < 4; ++i) STORE_HL(dh, dl, 16 + i * 4, z);
            }
        }
    }
    __syncthreads();

    const int w = tid >> 6, lane = tid & 63;
    const int mr = lane & 15, quad = lane >> 4;
    const int rt = w & 1, cgp = w >> 1;

    // ---- Phase B: z1 tile (16 rows x 64 cols per wave) ----
    f32x4 acc[4];
    {
        const ushort* aH = sHi + (rt * 16 + mr) * SXS;
        const ushort* aL = sLo + (rt * 16 + mr) * SXS;
        #pragma unroll
        for (int t = 0; t < 4; ++t) acc[t] = (f32x4){0.f, 0.f, 0.f, 0.f};
        for (int ks = 0; ks < nK; ++ks) {
            const int k0 = ks * 32 + quad * 8;
            s16x8 ahi = *(const s16x8*)(aH + k0);
            s16x8 alo = *(const s16x8*)(aL + k0);
            #pragma unroll
            for (int t = 0; t < 4; ++t) {
                const int nc = cgp * 64 + t * 16 + mr;
                s16x8 bhi = *(const s16x8*)(wBhi + nc * wk + k0);
                s16x8 blo = *(const s16x8*)(wBlo + nc * wk + k0);
                acc[t] = __builtin_amdgcn_mfma_f32_16x16x32_bf16(ahi, bhi, acc[t], 0, 0, 0);
                acc[t] = __builtin_amdgcn_mfma_f32_16x16x32_bf16(ahi, blo, acc[t], 0, 0, 0);
                acc[t] = __builtin_amdgcn_mfma_f32_16x16x32_bf16(alo, bhi, acc[t], 0, 0, 0);
            }
        }
    }
    __syncthreads();

    {   // ---- BN (fold b1) + ReLU -> Z hi/lo ----
        #pragma unroll
        for (int t = 0; t < 4; ++t) {
            const int c = cgp * 64 + t * 16 + mr;
            float sc = gL[c] * rsqrtf(vrL[c] + EPS);
            float sh = (b1L[c] - mnL[c]) * sc + btL[c];
            #pragma unroll
            for (int reg = 0; reg < 4; ++reg) {
                float z = fmaxf(acc[t][reg] * sc + sh, 0.f);
                int m = rt * 16 + quad * 4 + reg;
                ushort hh = f2bf(z);
                sHi[m * SXS + c] = hh;
                sLo[m * SXS + c] = f2bf(z - bf2f(hh));
            }
        }
    }
    __syncthreads();

    {   // ---- Phase C: z2 tile (16 rows x 32 cols per wave) ----
        const ushort* zH = sHi + (rt * 16 + mr) * SXS;
        const ushort* zL = sLo + (rt * 16 + mr) * SXS;
        f32x4 a2[2];
        #pragma unroll
        for (int t = 0; t < 2; ++t) a2[t] = (f32x4){0.f, 0.f, 0.f, 0.f};
        #pragma unroll
        for (int ks = 0; ks < 4; ++ks) {
            const int k0 = ks * 32 + quad * 8;
            s16x8 ahi = *(const s16x8*)(zH + k0);
            s16x8 alo = *(const s16x8*)(zL + k0);
            #pragma unroll
            for (int t = 0; t < 2; ++t) {
                const int nc = (cgp * 2 + t) * 16 + mr;
                s16x8 bhi = *(const s16x8*)(w2hiL + nc * 128 + k0);
                s16x8 blo = *(const s16x8*)(w2loL + nc * 128 + k0);
                a2[t] = __builtin_amdgcn_mfma_f32_16x16x32_bf16(ahi, bhi, a2[t], 0, 0, 0);
                a2[t] = __builtin_amdgcn_mfma_f32_16x16x32_bf16(ahi, blo, a2[t], 0, 0, 0);
                a2[t] = __builtin_amdgcn_mfma_f32_16x16x32_bf16(alo, bhi, a2[t], 0, 0, 0);
            }
        }
        #pragma unroll
        for (int t = 0; t < 2; ++t) {
            const int c = (cgp * 2 + t) * 16 + mr;
            float bb = b2L[c];
            #pragma unroll
            for (int reg = 0; reg < 4; ++reg) {
                int m = rt * 16 + quad * 4 + reg;
                int n = n0 + m;
                float o = a2[t][reg] + bb;
                if (relu_out) o = fmaxf(o, 0.f);
                if (store_bf16) ((ushort*)h_out)[n * H + c] = f2bf(o);
                else            ((float*)h_out)[n * H + c] = o;
            }
        }
    }
    __syncthreads();
}

static __device__ __forceinline__ void run_mlp_tile(const GP& p, int l, int tb,
                                                    int tid, ushort* sm) {
    if (l == 0)
        mlp_tile(p, tb, tid, sm, p.w0hi, p.w0lo, 32, 1, p.w2hi, p.w2lo,
                 p.b1, p.gamma, p.beta, p.bnm, p.bnv, p.b2, 0, 1, p.hb, 1);
    else if (l == 1)
        mlp_tile(p, tb, tid, sm, p.wbhi, p.wblo, 96, 3,
                 p.w2hi + 8192, p.w2lo + 8192,
                 p.b1 + 128, p.gamma + 128, p.beta + 128, p.bnm + 128, p.bnv + 128,
                 p.b2 + 64, 1, 1, p.hb, 1);
    else
        mlp_tile(p, tb, tid, sm, p.wbhi + 12288, p.wblo + 12288, 96, 3,
                 p.w2hi + 16384, p.w2lo + 16384,
                 p.b1 + 256, p.gamma + 256, p.beta + 256, p.bnm + 256, p.bnv + 256,
                 p.b2 + 128, 1, 0, p.out, 0);
}

// ============ cooperative single-dispatch path ============
__global__ __launch_bounds__(256, 2) void k_all(GP p) {
    __shared__ ushort sm[2 * 32 * SXS];   // 17408 B
    cg::grid_group grid = cg::this_grid();
    const int tid = threadIdx.x, bid = blockIdx.x;

    for (int i = bid * 256 + tid; i < 2 * N; i += GRID * 256) p.deg[i] = 0;
    grid.sync();

    for (int e = bid * 256 + tid; e < E; e += GRID * 256) count_work(p, e);
    for (int t = bid * 256 + tid; t < 53248; t += GRID * 256) wprep_work(p, t);
    grid.sync();

    if (bid < 79) {
        int idx = bid * 256 + tid;
        int v = (idx < N) ? p.deg[idx] : 0;
        int incl = blk_scan(v, tid, (int*)sm);
        if (idx < N) p.rowptr[idx] = incl - v;
        if (tid == 255) p.bsum[bid] = incl;
    }
    grid.sync();
    if (bid == 0) {
        int v = (tid < 79) ? p.bsum[tid] : 0;
        int incl = blk_scan(v, tid, (int*)sm);
        if (tid < 80) p.boff[tid] = incl - v;
        if (tid == 79) p.rowptr[N] = incl;
    }
    grid.sync();
    if (bid < 79) {
        int idx = bid * 256 + tid;
        if (idx < N) p.rowptr[idx] += p.boff[bid];
    }
    grid.sync();

    for (int e = bid * 256 + tid; e < E; e += GRID * 256) {
        int s = p.ei[e], d = p.ei[E + e];
        p.pk2[p.rowptr[s] + p.epos[e]] = make_int2(d, e);
    }
    grid.sync();

    for (int t = bid * 256 + tid; t < N * 16; t += GRID * 256) attr_work(p, t);
    grid.sync();

    for (int tb = bid; tb < N / 32; tb += GRID) run_mlp_tile(p, 0, tb, tid, sm);
    grid.sync();
    gather_phase(p, tid, bid, GRID);
    grid.sync();
    for (int tb = bid; tb < N / 32; tb += GRID) run_mlp_tile(p, 1, tb, tid, sm);
    grid.sync();
    gather_phase(p, tid, bid, GRID);
    grid.sync();
    for (int tb = bid; tb < N / 32; tb += GRID) run_mlp_tile(p, 2, tb, tid, sm);
}

// ============ fallback multi-dispatch path (R6-equivalent) ============
__global__ void k_count_s(GP p) {
    int e = blockIdx.x * 256 + threadIdx.x;
    if (e < E) count_work(p, e);
}
__global__ void k_wprep_s(GP p) {
    int t = blockIdx.x * 256 + threadIdx.x;
    if (t < 53248) wprep_work(p, t);
}
__global__ void k_scan_s(GP p) {
    __shared__ int wsum[16];
    const int tid = threadIdx.x, lane = tid & 63, w = tid >> 6;
    const int i0 = tid * 20;
    int loc[20];
    const int4* dv = (const int4*)(p.deg + i0);
    #pragma unroll
    for (int jj = 0; jj < 5; ++jj) {
        int4 v = dv[jj];
        int b = jj * 4;
        loc[b + 0] = (i0 + b + 0 < N) ? v.x : 0;
        loc[b + 1] = (i0 + b + 1 < N) ? v.y : 0;
        loc[b + 2] = (i0 + b + 2 < N) ? v.z : 0;
        loc[b + 3] = (i0 + b + 3 < N) ? v.w : 0;
    }
    int s = 0;
    #pragma unroll
    for (int j = 0; j < 20; ++j) s += loc[j];
    int t = s;
    #pragma unroll
    for (int off = 1; off < 64; off <<= 1) {
        int u = __shfl_up(t, off);
        if (lane >= off) t += u;
    }
    if (lane == 63) wsum[w] = t;
    __syncthreads();
    if (w == 0 && lane < 16) {
        int u = wsum[lane];
        #pragma unroll
        for (int off = 1; off < 16; off <<= 1) {
            int z = __shfl_up(u, off);
            if (lane >= off) u += z;
        }
        wsum[lane] = u;
    }
    __syncthreads();
    int excl = ((w == 0) ? 0 : wsum[w - 1]) + t - s;
    int o[20];
    #pragma unroll
    for (int j = 0; j < 20; ++j) { o[j] = excl; excl += loc[j]; }
    int4* rv = (int4*)(p.rowptr + i0);
    #pragma unroll
    for (int jj = 0; jj < 5; ++jj) {
        int b = jj * 4;
        if (i0 + b <= N)
            rv[jj] = make_int4(o[b + 0], o[b + 1], o[b + 2], o[b + 3]);
    }
}
__global__ void k_fill_s(GP p) {
    int e = blockIdx.x * 256 + threadIdx.x;
    if (e >= E) return;
    int s = p.ei[e], d = p.ei[E + e];
    p.pk2[p.rowptr[s] + p.epos[e]] = make_int2(d, e);
}
__global__ void k_attr_s(GP p) {
    int t = blockIdx.x * 256 + threadIdx.x;
    if (t < N * 16) attr_work(p, t);
}
__global__ __launch_bounds__(256, 8) void k_gather_s(GP p) {
    gather_phase(p, threadIdx.x, blockIdx.x, gridDim.x);
}
__global__ __launch_bounds__(256, 4) void k_mlp_s(GP p, int l) {
    __shared__ ushort sm[2 * 32 * SXS];
    run_mlp_tile(p, l, blockIdx.x, threadIdx.x, sm);
}

extern "C" void kernel_launch(void* const* d_in, const int* in_sizes, int n_in,
                              void* d_out, int out_size, void* d_ws, size_t ws_size,
                              hipStream_t stream) {
    GP gp;
    gp.x     = (const int*)d_in[0];
    gp.ei    = (const int*)d_in[1];
    gp.eattr = (const float*)d_in[2];
    gp.emb0  = (const float*)d_in[3];
    gp.We    = (const float*)d_in[4];
    gp.be    = (const float*)d_in[5];
    gp.W1    = (const float*)d_in[6];
    gp.b1    = (const float*)d_in[7];
    gp.gamma = (const float*)d_in[8];
    gp.beta  = (const float*)d_in[9];
    gp.bnm   = (const float*)d_in[10];
    gp.bnv   = (const float*)d_in[11];
    gp.W2    = (const float*)d_in[12];
    gp.b2    = (const float*)d_in[13];
    gp.slip  = (const int*)d_in[14];
    gp.sltp  = (const int*)d_in[15];
    gp.out   = (float*)d_out;

    gp.deg    = (int*)d_ws + OFF_DEG;
    gp.cnt1   = (int*)d_ws + OFF_CNT1;
    gp.attr   = (float*)d_ws + OFF_ATTR;
    gp.rowptr = (int*)d_ws + OFF_ROWPTR;
    gp.epos   = (int*)d_ws + OFF_EPOS;
    gp.pk2    = (int2*)((int*)d_ws + OFF_PK2);
    gp.hb     = (ushort*)((int*)d_ws + OFF_HB);
    gp.aggF   = (float*)d_ws + OFF_AGG;
    gp.w0hi   = (ushort*)((int*)d_ws + OFF_W0HI);
    gp.w0lo   = (ushort*)((int*)d_ws + OFF_W0LO);
    gp.wbhi   = (ushort*)((int*)d_ws + OFF_WBHI);
    gp.wblo   = (ushort*)((int*)d_ws + OFF_WBLO);
    gp.w2hi   = (ushort*)((int*)d_ws + OFF_W2HI);
    gp.w2lo   = (ushort*)((int*)d_ws + OFF_W2LO);
    gp.bsum   = (int*)d_ws + OFF_BSUM;
    gp.boff   = (int*)d_ws + OFF_BOFF;

    void* args[] = { &gp };
    hipError_t err = hipLaunchCooperativeKernel((const void*)k_all, dim3(GRID),
                                                dim3(256), args, 0, stream);
    if (err != hipSuccess) {
        // fallback: proven multi-dispatch path
        hipMemsetAsync(d_ws, 0, (size_t)(2 * N) * 4, stream);
        k_count_s<<<dim3((E + 255) / 256), dim3(256), 0, stream>>>(gp);
        k_wprep_s<<<dim3(208), dim3(256), 0, stream>>>(gp);
        k_scan_s<<<dim3(1), dim3(1024), 0, stream>>>(gp);
        k_fill_s<<<dim3((E + 255) / 256), dim3(256), 0, stream>>>(gp);
        k_attr_s<<<dim3((N * 16 + 255) / 256), dim3(256), 0, stream>>>(gp);
        k_mlp_s<<<dim3(N / 32), dim3(256), 0, stream>>>(gp, 0);
        k_gather_s<<<dim3(N / 4), dim3(256), 0, stream>>>(gp);
        k_mlp_s<<<dim3(N / 32), dim3(256), 0, stream>>>(gp, 1);
        k_gather_s<<<dim3(N / 4), dim3(256), 0, stream>>>(gp);
        k_mlp_s<<<dim3(N / 32), dim3(256), 0, stream>>>(gp, 2);
    }
}